// Round 8
// baseline (3199.977 us; speedup 1.0000x reference)
//
#include <hip/hip_runtime.h>
#include <hip/hip_fp16.h>
#include <math.h>

#define N_NODES 100000
#define DIM 64
#define E_REL 1600000
#define E_QQ 1000000

#define NBUCK 392     // buckets of 256 dst nodes (100000/256 -> 391 used)
#define NPB 256       // nodes per bucket
#define BCAP 4608     // >= Poisson(4096) + 8 sigma
#define CHUNK_E 8192
#define P1_BLOCKS ((E_REL + CHUNK_E - 1) / CHUNK_E)  // 196

// ---------------------------------------------------------------------------
// Phase 1: bin edges by dst-bucket (packed (dlocal<<17)|src, dlocal 8b) and
// by src-bucket (ushort src&255). LDS counts; ~2*NBUCK global atomics/block.
// ---------------------------------------------------------------------------
__global__ __launch_bounds__(256) void bin_edges(
    const int* __restrict__ src, const int* __restrict__ dst,
    int* __restrict__ gcur_d, int* __restrict__ gcur_s,
    unsigned* __restrict__ bin_d, unsigned short* __restrict__ bin_s) {
  __shared__ int cd[NBUCK];
  __shared__ int cs[NBUCK];
  int t = threadIdx.x;
  for (int i = t; i < NBUCK; i += 256) { cd[i] = 0; cs[i] = 0; }
  __syncthreads();
  int e0 = blockIdx.x * CHUNK_E;
  int e1 = e0 + CHUNK_E;
  if (e1 > E_REL) e1 = E_REL;
  for (int e = e0 + t; e < e1; e += 256) {
    atomicAdd(&cd[dst[e] >> 8], 1);
    atomicAdd(&cs[src[e] >> 8], 1);
  }
  __syncthreads();
  for (int i = t; i < NBUCK; i += 256) {
    cd[i] = atomicAdd(&gcur_d[i], cd[i]);
    cs[i] = atomicAdd(&gcur_s[i], cs[i]);
  }
  __syncthreads();
  for (int e = e0 + t; e < e1; e += 256) {
    int s = src[e];
    int d = dst[e];
    int bd = d >> 8;
    int bs = s >> 8;
    int pd = atomicAdd(&cd[bd], 1);
    int ps = atomicAdd(&cs[bs], 1);
    if ((unsigned)pd < BCAP)
      bin_d[(size_t)bd * BCAP + pd] = (unsigned)(((d & 255) << 17) | s);
    if ((unsigned)ps < BCAP)
      bin_s[(size_t)bs * BCAP + ps] = (unsigned short)(s & 255);
  }
}

// ---------------------------------------------------------------------------
// Phase 2: blocks 0..NBUCK-1: per-bucket counting sort of bin_d by src>>8
// (coarse 256-node src groups, unstable OK) + dst-deg histogram -> degv.
// Blocks NBUCK..2NBUCK-1: src histogram -> csrc = rsqrt(outdeg).
// ---------------------------------------------------------------------------
__global__ __launch_bounds__(256) void sort_tables(
    const int* __restrict__ gcur_d, const int* __restrict__ gcur_s,
    unsigned* __restrict__ bin_d, const unsigned short* __restrict__ bin_s,
    int* __restrict__ degv, float* __restrict__ csrc) {
  __shared__ unsigned es[BCAP];
  __shared__ unsigned et[BCAP];
  __shared__ int hist[512];
  __shared__ int dh[256];
  __shared__ int ls[256];
  int t = threadIdx.x;
  if (blockIdx.x >= NBUCK) {
    int b = blockIdx.x - NBUCK;
    dh[t] = 0;
    __syncthreads();
    int n = gcur_s[b];
    if (n > BCAP) n = BCAP;
    const unsigned short* bs = bin_s + (size_t)b * BCAP;
    for (int i = t; i < n; i += 256) atomicAdd(&dh[bs[i]], 1);
    __syncthreads();
    int node = (b << 8) + t;
    if (node < N_NODES) csrc[node] = dh[t] > 0 ? rsqrtf((float)dh[t]) : 0.0f;
    return;
  }
  int b = blockIdx.x;
  int n = gcur_d[b];
  if (n > BCAP) n = BCAP;
  unsigned* bd = bin_d + (size_t)b * BCAP;
  dh[t] = 0;
  hist[t] = 0;
  hist[t + 256] = 0;
  __syncthreads();
  for (int i = t; i < n; i += 256) {
    unsigned e = bd[i];
    es[i] = e;
    atomicAdd(&dh[e >> 17], 1);
    atomicAdd(&hist[(e & 0x1FFFF) >> 8], 1);
  }
  __syncthreads();
  int node = (b << 8) + t;
  if (node < N_NODES) degv[node] = dh[t];
  // exclusive scan over hist[512]
  int c0 = hist[2 * t], c1 = hist[2 * t + 1];
  ls[t] = c0 + c1;
  __syncthreads();
  for (int off = 1; off < 256; off <<= 1) {
    int v = (t >= off) ? ls[t - off] : 0;
    __syncthreads();
    ls[t] += v;
    __syncthreads();
  }
  int base = ls[t] - (c0 + c1);
  __syncthreads();
  hist[2 * t] = base;
  hist[2 * t + 1] = base + c0;
  __syncthreads();
  for (int i = t; i < n; i += 256) {
    unsigned e = es[i];
    int pos = atomicAdd(&hist[(e & 0x1FFFF) >> 8], 1);
    et[pos] = e;
  }
  __syncthreads();
  for (int i = t; i < n; i += 256) bd[i] = et[i];
}

__device__ inline unsigned pack_h2(float a, float b) {
  __half2 h = __floats2half2_rn(a, b);
  return *reinterpret_cast<unsigned*>(&h);
}

// ---------------------------------------------------------------------------
// Y[row] = fp16( csrc[row] * (X[row] @ W) )   fp32 input, thread-per-row
// ---------------------------------------------------------------------------
__global__ __launch_bounds__(256) void gemm_in_h(
    const float* __restrict__ X, const float* __restrict__ W,
    const float* __restrict__ csrc, __half* __restrict__ Y) {
  __shared__ float Ws[64 * 64];
  for (int t = threadIdx.x; t < 64 * 64; t += 256) Ws[t] = W[t];
  __syncthreads();
  int row = blockIdx.x * 256 + threadIdx.x;
  if (row >= N_NODES) return;
  const float4* xr = (const float4*)(X + (size_t)row * 64);
  float acc[64];
#pragma unroll
  for (int j = 0; j < 64; j++) acc[j] = 0.0f;
#pragma unroll
  for (int k4 = 0; k4 < 16; k4++) {
    float4 xv = xr[k4];
    const float* w0 = &Ws[(k4 * 4 + 0) * 64];
    const float* w1 = &Ws[(k4 * 4 + 1) * 64];
    const float* w2 = &Ws[(k4 * 4 + 2) * 64];
    const float* w3 = &Ws[(k4 * 4 + 3) * 64];
#pragma unroll
    for (int j = 0; j < 64; j++)
      acc[j] += xv.x * w0[j] + xv.y * w1[j] + xv.z * w2[j] + xv.w * w3[j];
  }
  float s = csrc[row];
  uint4* yr = (uint4*)(Y + (size_t)row * 64);
#pragma unroll
  for (int j8 = 0; j8 < 8; j8++) {
    uint4 u;
    u.x = pack_h2(s * acc[j8 * 8 + 0], s * acc[j8 * 8 + 1]);
    u.y = pack_h2(s * acc[j8 * 8 + 2], s * acc[j8 * 8 + 3]);
    u.z = pack_h2(s * acc[j8 * 8 + 4], s * acc[j8 * 8 + 5]);
    u.w = pack_h2(s * acc[j8 * 8 + 6], s * acc[j8 * 8 + 7]);
    yr[j8] = u;
  }
}

// ---------------------------------------------------------------------------
// Y[row] = fp16( csrc[row] * (H[row] @ W) )   fp16 input variant
// ---------------------------------------------------------------------------
__global__ __launch_bounds__(256) void gemm_mid_h(
    const __half* __restrict__ X, const float* __restrict__ W,
    const float* __restrict__ csrc, __half* __restrict__ Y) {
  __shared__ float Ws[64 * 64];
  for (int t = threadIdx.x; t < 64 * 64; t += 256) Ws[t] = W[t];
  __syncthreads();
  int row = blockIdx.x * 256 + threadIdx.x;
  if (row >= N_NODES) return;
  const uint4* xr = (const uint4*)(X + (size_t)row * 64);
  float acc[64];
#pragma unroll
  for (int j = 0; j < 64; j++) acc[j] = 0.0f;
#pragma unroll
  for (int k8 = 0; k8 < 8; k8++) {
    uint4 u = xr[k8];
    float2 f0 = __half22float2(*(__half2*)&u.x);
    float2 f1 = __half22float2(*(__half2*)&u.y);
    float2 f2 = __half22float2(*(__half2*)&u.z);
    float2 f3 = __half22float2(*(__half2*)&u.w);
    const float* w = &Ws[(k8 * 8) * 64];
#pragma unroll
    for (int j = 0; j < 64; j++)
      acc[j] += f0.x * w[0 * 64 + j] + f0.y * w[1 * 64 + j] +
                f1.x * w[2 * 64 + j] + f1.y * w[3 * 64 + j] +
                f2.x * w[4 * 64 + j] + f2.y * w[5 * 64 + j] +
                f3.x * w[6 * 64 + j] + f3.y * w[7 * 64 + j];
  }
  float s = csrc[row];
  uint4* yr = (uint4*)(Y + (size_t)row * 64);
#pragma unroll
  for (int j8 = 0; j8 < 8; j8++) {
    uint4 u;
    u.x = pack_h2(s * acc[j8 * 8 + 0], s * acc[j8 * 8 + 1]);
    u.y = pack_h2(s * acc[j8 * 8 + 2], s * acc[j8 * 8 + 3]);
    u.z = pack_h2(s * acc[j8 * 8 + 4], s * acc[j8 * 8 + 5]);
    u.w = pack_h2(s * acc[j8 * 8 + 6], s * acc[j8 * 8 + 7]);
    yr[j8] = u;
  }
}

// ---------------------------------------------------------------------------
// Streaming aggregation: one block per 256-node dst-bucket, fp32 accumulators
// in LDS (64 KB), edges pre-sorted by coarse src group -> co-resident blocks
// walk the same ascending Y window (L2-resident per XCD).
// Wave layout: 8 groups x 8 lanes; group handles one edge; lane loads 16 B
// (8 fp16 feats) and ds_adds 8 floats with additive swizzle (f+dl)&63 to
// spread banks across groups.
// PHASE 0: Hout = fp16(relu(acc*cd + bias))            (conv1 -> h)
// PHASE 1: z = relu(acc*cd + bias)                      (conv2 pos)
// PHASE 2: z -= relu(...); uv[node] = {z.Wc pieces}     (conv2 neg)
// ---------------------------------------------------------------------------
template <int PHASE>
__global__ __launch_bounds__(256) void gather_acc(
    const __half* __restrict__ Y, const unsigned* __restrict__ bin_d,
    const int* __restrict__ gcur_d, const int* __restrict__ degv,
    const float* __restrict__ bias, __half* __restrict__ Hout,
    float* __restrict__ z, float* __restrict__ uv,
    const float* __restrict__ Wc) {
  __shared__ float acc[NPB * 64];  // feat-rotated storage: [dl][(f+dl)&63]
  int t = threadIdx.x;
  float4 z4 = make_float4(0.f, 0.f, 0.f, 0.f);
  float4* ap = (float4*)acc;
  for (int i = t; i < NPB * 16; i += 256) ap[i] = z4;
  __syncthreads();
  int b = blockIdx.x;
  int n = gcur_d[b];
  if (n > BCAP) n = BCAP;
  const unsigned* be = bin_d + (size_t)b * BCAP;
  int lane = t & 63;
  int l = lane & 7, q = lane >> 3;
  int wslot = t >> 6;
  const __half* Yl = Y + 8 * l;
  for (int base = wslot * 64; base < n; base += 256) {
    int lim = n - base;
    unsigned sv = (base + lane < n) ? be[base + lane] : 0u;
    for (int jj = 0; jj < 8; jj += 2) {
      int i0 = jj * 8 + q;
      int i1 = i0 + 8;
      unsigned ea = __shfl(sv, i0);
      unsigned eb = __shfl(sv, i1);
      bool pa = i0 < lim, pb = i1 < lim;
      uint4 ua, ub;
      int da = 0, db = 0, aa = 0, ab = 0;
      if (pa) {
        int s = ea & 0x1FFFF;
        da = ea >> 17;
        aa = (8 * l + da) & 63;
        ua = *(const uint4*)(Yl + (size_t)s * 64);
      }
      if (pb) {
        int s = eb & 0x1FFFF;
        db = eb >> 17;
        ab = (8 * l + db) & 63;
        ub = *(const uint4*)(Yl + (size_t)s * 64);
      }
      if (pa) {
        float2 f0 = __half22float2(*(__half2*)&ua.x);
        float2 f1 = __half22float2(*(__half2*)&ua.y);
        float2 f2 = __half22float2(*(__half2*)&ua.z);
        float2 f3 = __half22float2(*(__half2*)&ua.w);
        float* r = acc + da * 64;
        atomicAdd(&r[aa], f0.x);
        atomicAdd(&r[(aa + 1) & 63], f0.y);
        atomicAdd(&r[(aa + 2) & 63], f1.x);
        atomicAdd(&r[(aa + 3) & 63], f1.y);
        atomicAdd(&r[(aa + 4) & 63], f2.x);
        atomicAdd(&r[(aa + 5) & 63], f2.y);
        atomicAdd(&r[(aa + 6) & 63], f3.x);
        atomicAdd(&r[(aa + 7) & 63], f3.y);
      }
      if (pb) {
        float2 f0 = __half22float2(*(__half2*)&ub.x);
        float2 f1 = __half22float2(*(__half2*)&ub.y);
        float2 f2 = __half22float2(*(__half2*)&ub.z);
        float2 f3 = __half22float2(*(__half2*)&ub.w);
        float* r = acc + db * 64;
        atomicAdd(&r[ab], f0.x);
        atomicAdd(&r[(ab + 1) & 63], f0.y);
        atomicAdd(&r[(ab + 2) & 63], f1.x);
        atomicAdd(&r[(ab + 3) & 63], f1.y);
        atomicAdd(&r[(ab + 4) & 63], f2.x);
        atomicAdd(&r[(ab + 5) & 63], f2.y);
        atomicAdd(&r[(ab + 6) & 63], f3.x);
        atomicAdd(&r[(ab + 7) & 63], f3.y);
      }
    }
  }
  __syncthreads();
  // ---- epilogue: lane-parallel per node ----
  int node0 = b << 8;
  float bv = bias[lane];
  float w0 = 0.f, w1 = 0.f, w2 = 0.f, w3 = 0.f;
  if (PHASE == 2) {
    w0 = Wc[lane * 2 + 0];
    w1 = Wc[lane * 2 + 1];
    w2 = Wc[(64 + lane) * 2 + 0];
    w3 = Wc[(64 + lane) * 2 + 1];
  }
  for (int i = wslot; i < NPB; i += 4) {
    int node = node0 + i;
    if (node >= N_NODES) break;
    int dg = degv[node];
    float cd = dg > 0 ? rsqrtf((float)dg) : 0.0f;
    float av = acc[i * 64 + ((lane + i) & 63)];  // un-swizzle: feat 'lane'
    float v = fmaxf(av * cd + bv, 0.0f);
    if (PHASE == 0) {
      Hout[(size_t)node * 64 + lane] = __float2half(v);
    } else if (PHASE == 1) {
      z[(size_t)node * 64 + lane] = v;
    } else {
      size_t zi = (size_t)node * 64 + lane;
      float r = z[zi] - v;
      z[zi] = r;
      float p0 = r * w0, p1 = r * w1, p2 = r * w2, p3 = r * w3;
#pragma unroll
      for (int o = 1; o < 64; o <<= 1) {
        p0 += __shfl_xor(p0, o);
        p1 += __shfl_xor(p1, o);
        p2 += __shfl_xor(p2, o);
        p3 += __shfl_xor(p3, o);
      }
      if (lane == 0)
        *(float4*)(uv + (size_t)node * 4) = make_float4(p0, p1, p2, p3);
    }
  }
}

// ---------------------------------------------------------------------------
// probs[e] = sigmoid(u(s) + v(d) + bc)  — factorized classifier
// ---------------------------------------------------------------------------
__global__ __launch_bounds__(256) void classify_kernel(
    const float* __restrict__ uv, const int* __restrict__ ei,
    const float* __restrict__ bc, float* __restrict__ out) {
  int e = blockIdx.x * 256 + threadIdx.x;
  if (e >= E_QQ) return;
  int s = ei[e];
  int d = ei[E_QQ + e];
  float4 us = *((const float4*)(uv + (size_t)s * 4));
  float4 vd = *((const float4*)(uv + (size_t)d * 4));
  float l0 = us.x + vd.z + bc[0];
  float l1 = us.y + vd.w + bc[1];
  float2 o;
  o.x = 1.0f / (1.0f + __expf(-l0));
  o.y = 1.0f / (1.0f + __expf(-l1));
  *((float2*)(out + (size_t)e * 2)) = o;
}

extern "C" void kernel_launch(void* const* d_in, const int* in_sizes, int n_in,
                              void* d_out, int out_size, void* d_ws,
                              size_t ws_size, hipStream_t stream) {
  const float* x   = (const float*)d_in[0];
  const float* W0p = (const float*)d_in[1];
  const float* b0p = (const float*)d_in[2];
  const float* W0n = (const float*)d_in[3];
  const float* b0n = (const float*)d_in[4];
  const float* W1p = (const float*)d_in[5];
  const float* b1p = (const float*)d_in[6];
  const float* W1n = (const float*)d_in[7];
  const float* b1n = (const float*)d_in[8];
  const float* Wc  = (const float*)d_in[9];
  const float* bc  = (const float*)d_in[10];
  const int* sp = (const int*)d_in[11];
  const int* dp = (const int*)d_in[12];
  const int* sn = (const int*)d_in[13];
  const int* dn = (const int*)d_in[14];
  const int* ei = (const int*)d_in[15];

  // workspace layout (~39 MB)
  float* csrc = (float*)d_ws;                              // N (reused pos/neg)
  int* degv = (int*)(csrc + N_NODES);                      // N (reused)
  float* uv = (float*)(degv + N_NODES);                    // 4N
  int* gcur = (int*)(uv + 4 * N_NODES);                    // 800 (2*NBUCK+pad)
  unsigned* bin_d = (unsigned*)(gcur + 800);               // NBUCK*BCAP uint
  unsigned short* bin_s =
      (unsigned short*)(bin_d + (size_t)NBUCK * BCAP);     // NBUCK*BCAP ushort
  __half* A = (__half*)(bin_s + (size_t)NBUCK * BCAP);     // N*64 fp16
  __half* B = A + (size_t)N_NODES * 64;                    // N*64 fp16

  float* z     = (float*)d_out;                 // N*64 fp32
  float* probs = z + (size_t)N_NODES * 64;      // E_Q*2 fp32

  int* gcur_d = gcur;
  int* gcur_s = gcur + NBUCK;

  const int gemmGrid = (N_NODES + 255) / 256;

  // ---- POS relation ----
  hipMemsetAsync(gcur, 0, 2 * NBUCK * sizeof(int), stream);
  bin_edges<<<P1_BLOCKS, 256, 0, stream>>>(sp, dp, gcur_d, gcur_s, bin_d, bin_s);
  sort_tables<<<2 * NBUCK, 256, 0, stream>>>(gcur_d, gcur_s, bin_d, bin_s,
                                             degv, csrc);
  gemm_in_h<<<gemmGrid, 256, 0, stream>>>(x, W0p, csrc, A);
  gather_acc<0><<<NBUCK, 256, 0, stream>>>(A, bin_d, gcur_d, degv, b0p, B,
                                           nullptr, nullptr, Wc);
  gemm_mid_h<<<gemmGrid, 256, 0, stream>>>(B, W1p, csrc, A);
  gather_acc<1><<<NBUCK, 256, 0, stream>>>(A, bin_d, gcur_d, degv, b1p,
                                           nullptr, z, nullptr, Wc);

  // ---- NEG relation ---- (bins/degv/csrc reused; pos consumers done)
  hipMemsetAsync(gcur, 0, 2 * NBUCK * sizeof(int), stream);
  bin_edges<<<P1_BLOCKS, 256, 0, stream>>>(sn, dn, gcur_d, gcur_s, bin_d, bin_s);
  sort_tables<<<2 * NBUCK, 256, 0, stream>>>(gcur_d, gcur_s, bin_d, bin_s,
                                             degv, csrc);
  gemm_in_h<<<gemmGrid, 256, 0, stream>>>(x, W0n, csrc, A);
  gather_acc<0><<<NBUCK, 256, 0, stream>>>(A, bin_d, gcur_d, degv, b0n, B,
                                           nullptr, nullptr, Wc);
  gemm_mid_h<<<gemmGrid, 256, 0, stream>>>(B, W1n, csrc, A);
  gather_acc<2><<<NBUCK, 256, 0, stream>>>(A, bin_d, gcur_d, degv, b1n,
                                           nullptr, z, uv, Wc);

  // ---- classifier (factorized) ----
  classify_kernel<<<(E_QQ + 255) / 256, 256, 0, stream>>>(uv, ei, bc, probs);
}

// Round 9
// 902.862 us; speedup vs baseline: 3.5443x; 3.5443x over previous
//
#include <hip/hip_runtime.h>
#include <hip/hip_fp16.h>
#include <math.h>

#define N_NODES 100000
#define DIM 64
#define E_REL 1600000
#define E_QQ 1000000

#define NBUCK 196      // ceil(100000 / 512) node buckets of 512
#define BCAP 9216      // capacity per bucket; expected 8192, +11 sigma slack
#define CHUNK_E 8192   // edges per phase-1 block
#define P1_BLOCKS ((E_REL + CHUNK_E - 1) / CHUNK_E)  // 196
#define NBLK_N 1563    // node-blocks per feature pass (4 waves/block)
#define NCH 16         // features per chunk
#define N16 ((size_t)N_NODES * NCH)

// ---------------------------------------------------------------------------
// Phase 1: bin edges by dst-bucket (packed (dlocal<<17)|src) and by src-bucket
// (raw src). Per-block LDS counts; ~2*NBUCK global atomics per block reserve
// space; placement via LDS cursors + plain (write-back) stores.   [R7 proven]
// ---------------------------------------------------------------------------
__global__ __launch_bounds__(256) void bin_edges(
    const int* __restrict__ src, const int* __restrict__ dst,
    int* __restrict__ gcur_d, int* __restrict__ gcur_s,
    unsigned* __restrict__ bin_d, unsigned* __restrict__ bin_s) {
  __shared__ int cd[NBUCK];
  __shared__ int cs[NBUCK];
  int t = threadIdx.x;
  for (int i = t; i < NBUCK; i += 256) { cd[i] = 0; cs[i] = 0; }
  __syncthreads();
  int e0 = blockIdx.x * CHUNK_E;
  int e1 = e0 + CHUNK_E;
  if (e1 > E_REL) e1 = E_REL;
  for (int e = e0 + t; e < e1; e += 256) {
    atomicAdd(&cd[dst[e] >> 9], 1);
    atomicAdd(&cs[src[e] >> 9], 1);
  }
  __syncthreads();
  for (int i = t; i < NBUCK; i += 256) {
    cd[i] = atomicAdd(&gcur_d[i], cd[i]);
    cs[i] = atomicAdd(&gcur_s[i], cs[i]);
  }
  __syncthreads();
  for (int e = e0 + t; e < e1; e += 256) {
    int s = src[e];
    int d = dst[e];
    int bd = d >> 9;
    int bs = s >> 9;
    int pd = atomicAdd(&cd[bd], 1);
    int ps = atomicAdd(&cs[bs], 1);
    if ((unsigned)pd < BCAP)
      bin_d[(size_t)bd * BCAP + pd] = (unsigned)(((d & 511) << 17) | s);
    if ((unsigned)ps < BCAP)
      bin_s[(size_t)bs * BCAP + ps] = (unsigned)s;
  }
}

// ---------------------------------------------------------------------------
// Phase 2 fused: blocks 0..NBUCK-1 build the dst-CSR; blocks NBUCK.. build
// csrc = rsqrt(outdeg).                                           [R7 proven]
// ---------------------------------------------------------------------------
__global__ __launch_bounds__(256) void build_tables(
    const unsigned* __restrict__ bin_d, const int* __restrict__ gcur_d,
    const unsigned* __restrict__ bin_s, const int* __restrict__ gcur_s,
    int* __restrict__ offs, int* __restrict__ degv, int* __restrict__ srclist,
    float* __restrict__ csrc) {
  __shared__ int cnt[512];
  __shared__ int off0[512];
  __shared__ int curv[512];
  __shared__ int ls[256];
  int t = threadIdx.x;
  if (blockIdx.x >= NBUCK) {
    int b = blockIdx.x - NBUCK;
    cnt[t] = 0;
    cnt[t + 256] = 0;
    __syncthreads();
    int n = gcur_s[b];
    if (n > BCAP) n = BCAP;
    const unsigned* be = bin_s + (size_t)b * BCAP;
    for (int i = t; i < n; i += 256) atomicAdd(&cnt[be[i] & 511], 1);
    __syncthreads();
    int node0 = b << 9;
    for (int i = t; i < 512; i += 256) {
      int node = node0 + i;
      if (node < N_NODES) {
        int d = cnt[i];
        csrc[node] = d > 0 ? rsqrtf((float)d) : 0.0f;
      }
    }
    return;
  }
  int b = blockIdx.x;
  cnt[t] = 0;
  cnt[t + 256] = 0;
  __syncthreads();
  int n = gcur_d[b];
  if (n > BCAP) n = BCAP;
  const unsigned* be = bin_d + (size_t)b * BCAP;
  for (int i = t; i < n; i += 256) atomicAdd(&cnt[be[i] >> 17], 1);
  __syncthreads();
  int c0 = cnt[2 * t], c1 = cnt[2 * t + 1];
  ls[t] = c0 + c1;
  __syncthreads();
  for (int off = 1; off < 256; off <<= 1) {
    int v = (t >= off) ? ls[t - off] : 0;
    __syncthreads();
    ls[t] += v;
    __syncthreads();
  }
  int base = ls[t] - (c0 + c1);
  off0[2 * t] = base;
  off0[2 * t + 1] = base + c0;
  curv[2 * t] = base;
  curv[2 * t + 1] = base + c0;
  __syncthreads();
  for (int i = t; i < n; i += 256) {
    unsigned p = be[i];
    int dl = p >> 17;
    int pos = atomicAdd(&curv[dl], 1);
    srclist[(size_t)b * BCAP + pos] = (int)(p & 0x1FFFF);
  }
  __syncthreads();
  int node0 = b << 9;
  for (int i = t; i < 512; i += 256) {
    int node = node0 + i;
    if (node < N_NODES) {
      offs[node] = b * BCAP + off0[i];
      degv[node] = cnt[i];
    }
  }
}

__device__ inline unsigned pack_h2(float a, float b) {
  __half2 h = __floats2half2_rn(a, b);
  return *reinterpret_cast<unsigned*>(&h);
}

// ---------------------------------------------------------------------------
// Y_chunked = fp16( csrc[row] * (X[row] @ W) )  — writes 4 chunk tables
// Yc[c][node][16] so each gather pass touches a 3.2 MB L2-resident table.
// ---------------------------------------------------------------------------
__global__ __launch_bounds__(256) void gemm_in_h(
    const float* __restrict__ X, const float* __restrict__ W,
    const float* __restrict__ csrc, __half* __restrict__ Y) {
  __shared__ float Ws[64 * 64];
  for (int t = threadIdx.x; t < 64 * 64; t += 256) Ws[t] = W[t];
  __syncthreads();
  int row = blockIdx.x * 256 + threadIdx.x;
  if (row >= N_NODES) return;
  const float4* xr = (const float4*)(X + (size_t)row * 64);
  float acc[64];
#pragma unroll
  for (int j = 0; j < 64; j++) acc[j] = 0.0f;
#pragma unroll
  for (int k4 = 0; k4 < 16; k4++) {
    float4 xv = xr[k4];
    const float* w0 = &Ws[(k4 * 4 + 0) * 64];
    const float* w1 = &Ws[(k4 * 4 + 1) * 64];
    const float* w2 = &Ws[(k4 * 4 + 2) * 64];
    const float* w3 = &Ws[(k4 * 4 + 3) * 64];
#pragma unroll
    for (int j = 0; j < 64; j++)
      acc[j] += xv.x * w0[j] + xv.y * w1[j] + xv.z * w2[j] + xv.w * w3[j];
  }
  float s = csrc[row];
#pragma unroll
  for (int c = 0; c < 4; c++) {
    uint4* yc = (uint4*)(Y + (size_t)c * N16 + (size_t)row * NCH);
#pragma unroll
    for (int h = 0; h < 2; h++) {
      int f = c * 16 + h * 8;
      uint4 u;
      u.x = pack_h2(s * acc[f + 0], s * acc[f + 1]);
      u.y = pack_h2(s * acc[f + 2], s * acc[f + 3]);
      u.z = pack_h2(s * acc[f + 4], s * acc[f + 5]);
      u.w = pack_h2(s * acc[f + 6], s * acc[f + 7]);
      yc[h] = u;
    }
  }
}

// ---------------------------------------------------------------------------
// Same, fp16 chunked input (reads Hout chunk tables), chunked fp16 output.
// ---------------------------------------------------------------------------
__global__ __launch_bounds__(256) void gemm_mid_h(
    const __half* __restrict__ X, const float* __restrict__ W,
    const float* __restrict__ csrc, __half* __restrict__ Y) {
  __shared__ float Ws[64 * 64];
  for (int t = threadIdx.x; t < 64 * 64; t += 256) Ws[t] = W[t];
  __syncthreads();
  int row = blockIdx.x * 256 + threadIdx.x;
  if (row >= N_NODES) return;
  float acc[64];
#pragma unroll
  for (int j = 0; j < 64; j++) acc[j] = 0.0f;
#pragma unroll
  for (int c = 0; c < 4; c++) {
    const uint4* xr = (const uint4*)(X + (size_t)c * N16 + (size_t)row * NCH);
#pragma unroll
    for (int h = 0; h < 2; h++) {
      uint4 u = xr[h];
      float2 f0 = __half22float2(*(__half2*)&u.x);
      float2 f1 = __half22float2(*(__half2*)&u.y);
      float2 f2 = __half22float2(*(__half2*)&u.z);
      float2 f3 = __half22float2(*(__half2*)&u.w);
      const float* w = &Ws[(c * 16 + h * 8) * 64];
#pragma unroll
      for (int j = 0; j < 64; j++)
        acc[j] += f0.x * w[0 * 64 + j] + f0.y * w[1 * 64 + j] +
                  f1.x * w[2 * 64 + j] + f1.y * w[3 * 64 + j] +
                  f2.x * w[4 * 64 + j] + f2.y * w[5 * 64 + j] +
                  f3.x * w[6 * 64 + j] + f3.y * w[7 * 64 + j];
    }
  }
  float s = csrc[row];
#pragma unroll
  for (int c = 0; c < 4; c++) {
    uint4* yc = (uint4*)(Y + (size_t)c * N16 + (size_t)row * NCH);
#pragma unroll
    for (int h = 0; h < 2; h++) {
      int f = c * 16 + h * 8;
      uint4 u;
      u.x = pack_h2(s * acc[f + 0], s * acc[f + 1]);
      u.y = pack_h2(s * acc[f + 2], s * acc[f + 3]);
      u.z = pack_h2(s * acc[f + 4], s * acc[f + 5]);
      u.w = pack_h2(s * acc[f + 6], s * acc[f + 7]);
      yc[h] = u;
    }
  }
}

// ---------------------------------------------------------------------------
// Feature-split gather. Grid = 4 passes x NBLK_N blocks (pass-major: blocks
// of one pass are co-resident and only touch that pass's 3.2 MB Yc chunk ->
// L2-resident). Wave = 1 node; lanes = 16 edge-groups x 4 (8 B = 4 feats).
// PHASE 0: Hout chunk = fp16(relu(acc*cd+b));  PHASE 1: z chunk = relu(...);
// PHASE 2: z chunk -= relu(...).
// ---------------------------------------------------------------------------
template <int PHASE>
__global__ __launch_bounds__(256) void gather_split(
    const __half* __restrict__ Yc, const int* __restrict__ offs,
    const int* __restrict__ degv, const int* __restrict__ srclist,
    const float* __restrict__ bias, __half* __restrict__ Hout,
    float* __restrict__ z) {
  int p = blockIdx.x / NBLK_N;
  int nb = blockIdx.x - p * NBLK_N;
  int lane = threadIdx.x & 63;
  int wslot = threadIdx.x >> 6;
  int g = lane >> 2;   // edge slot 0..15
  int c = lane & 3;    // feature sub-quad
  const __half* Yp = Yc + (size_t)p * N16 + 4 * c;
  float4 bv = ((const float4*)bias)[p * 4 + c];
  for (int wid = nb * 4 + wslot; wid < N_NODES; wid += NBLK_N * 4) {
    int beg = offs[wid];
    int deg = degv[wid];
    float4 a0 = make_float4(0.f, 0.f, 0.f, 0.f);
    float4 a1 = make_float4(0.f, 0.f, 0.f, 0.f);
    for (int base = 0; base < deg; base += 64) {
      int chunk = deg - base;
      if (chunk > 64) chunk = 64;
      int sv = (base + lane < deg) ? srclist[beg + base + lane] : 0;
      for (int k = 0; k < chunk; k += 32) {
        int j0 = k + g;
        int j1 = k + 16 + g;
        int s0 = __shfl(sv, j0 & 63);
        int s1 = __shfl(sv, j1 & 63);
        if (j0 < chunk) {
          uint2 u = *(const uint2*)(Yp + (size_t)s0 * NCH);
          float2 f0 = __half22float2(*(__half2*)&u.x);
          float2 f1 = __half22float2(*(__half2*)&u.y);
          a0.x += f0.x; a0.y += f0.y; a0.z += f1.x; a0.w += f1.y;
        }
        if (j1 < chunk) {
          uint2 u = *(const uint2*)(Yp + (size_t)s1 * NCH);
          float2 f0 = __half22float2(*(__half2*)&u.x);
          float2 f1 = __half22float2(*(__half2*)&u.y);
          a1.x += f0.x; a1.y += f0.y; a1.z += f1.x; a1.w += f1.y;
        }
      }
    }
    a0.x += a1.x; a0.y += a1.y; a0.z += a1.z; a0.w += a1.w;
#pragma unroll
    for (int o = 4; o < 64; o <<= 1) {
      a0.x += __shfl_xor(a0.x, o);
      a0.y += __shfl_xor(a0.y, o);
      a0.z += __shfl_xor(a0.z, o);
      a0.w += __shfl_xor(a0.w, o);
    }
    float cd = deg > 0 ? rsqrtf((float)deg) : 0.0f;
    float4 v;
    v.x = fmaxf(a0.x * cd + bv.x, 0.0f);
    v.y = fmaxf(a0.y * cd + bv.y, 0.0f);
    v.z = fmaxf(a0.z * cd + bv.z, 0.0f);
    v.w = fmaxf(a0.w * cd + bv.w, 0.0f);
    if (PHASE == 0) {
      if (g == 0) {
        uint2 u;
        u.x = pack_h2(v.x, v.y);
        u.y = pack_h2(v.z, v.w);
        *(uint2*)(Hout + (size_t)p * N16 + (size_t)wid * NCH + 4 * c) = u;
      }
    } else if (PHASE == 1) {
      if (g == 0)
        *(float4*)(z + (size_t)wid * 64 + p * 16 + 4 * c) = v;
    } else {
      if (g == 0) {
        float4* zp = (float4*)(z + (size_t)wid * 64 + p * 16 + 4 * c);
        float4 zo = *zp;
        zo.x -= v.x; zo.y -= v.y; zo.z -= v.z; zo.w -= v.w;
        *zp = zo;
      }
    }
  }
}

// ---------------------------------------------------------------------------
// uv[node] = {z_row.Wc[0:64,:], z_row.Wc[64:128,:]}  (factorized classifier
// tables; z streamed coalesced)
// ---------------------------------------------------------------------------
__global__ __launch_bounds__(256) void uv_kernel(
    const float* __restrict__ z, const float* __restrict__ Wc,
    float* __restrict__ uv) {
  int wid = (blockIdx.x * 256 + threadIdx.x) >> 6;
  int lane = threadIdx.x & 63;
  if (wid >= N_NODES) return;
  float w0 = Wc[lane * 2 + 0];
  float w1 = Wc[lane * 2 + 1];
  float w2 = Wc[(64 + lane) * 2 + 0];
  float w3 = Wc[(64 + lane) * 2 + 1];
  float r = z[(size_t)wid * 64 + lane];
  float p0 = r * w0, p1 = r * w1, p2 = r * w2, p3 = r * w3;
#pragma unroll
  for (int o = 1; o < 64; o <<= 1) {
    p0 += __shfl_xor(p0, o);
    p1 += __shfl_xor(p1, o);
    p2 += __shfl_xor(p2, o);
    p3 += __shfl_xor(p3, o);
  }
  if (lane == 0)
    *(float4*)(uv + (size_t)wid * 4) = make_float4(p0, p1, p2, p3);
}

// ---------------------------------------------------------------------------
// probs[e] = sigmoid(u(s) + v(d) + bc)
// ---------------------------------------------------------------------------
__global__ __launch_bounds__(256) void classify_kernel(
    const float* __restrict__ uv, const int* __restrict__ ei,
    const float* __restrict__ bc, float* __restrict__ out) {
  int e = blockIdx.x * 256 + threadIdx.x;
  if (e >= E_QQ) return;
  int s = ei[e];
  int d = ei[E_QQ + e];
  float4 us = *((const float4*)(uv + (size_t)s * 4));
  float4 vd = *((const float4*)(uv + (size_t)d * 4));
  float l0 = us.x + vd.z + bc[0];
  float l1 = us.y + vd.w + bc[1];
  float2 o;
  o.x = 1.0f / (1.0f + __expf(-l0));
  o.y = 1.0f / (1.0f + __expf(-l1));
  *((float2*)(out + (size_t)e * 2)) = o;
}

extern "C" void kernel_launch(void* const* d_in, const int* in_sizes, int n_in,
                              void* d_out, int out_size, void* d_ws,
                              size_t ws_size, hipStream_t stream) {
  const float* x   = (const float*)d_in[0];
  const float* W0p = (const float*)d_in[1];
  const float* b0p = (const float*)d_in[2];
  const float* W0n = (const float*)d_in[3];
  const float* b0n = (const float*)d_in[4];
  const float* W1p = (const float*)d_in[5];
  const float* b1p = (const float*)d_in[6];
  const float* W1n = (const float*)d_in[7];
  const float* b1n = (const float*)d_in[8];
  const float* Wc  = (const float*)d_in[9];
  const float* bc  = (const float*)d_in[10];
  const int* sp = (const int*)d_in[11];
  const int* dp = (const int*)d_in[12];
  const int* sn = (const int*)d_in[13];
  const int* dn = (const int*)d_in[14];
  const int* ei = (const int*)d_in[15];

  // workspace (~50 MB)
  float* csrc = (float*)d_ws;                              // N
  int* degv = (int*)(csrc + N_NODES);                      // N
  int* offs = degv + N_NODES;                              // N
  float* uv = (float*)(offs + N_NODES);                    // 4N
  int* gcur = (int*)(uv + 4 * N_NODES);                    // 2*NBUCK (+pad)
  unsigned* bin_d = (unsigned*)(gcur + 2 * NBUCK + 2);     // NBUCK*BCAP
  unsigned* bin_s = bin_d + (size_t)NBUCK * BCAP;          // NBUCK*BCAP
  int* srclist = (int*)(bin_s + (size_t)NBUCK * BCAP);     // NBUCK*BCAP
  __half* A = (__half*)(srclist + (size_t)NBUCK * BCAP);   // 4 chunks, 12.8 MB
  __half* B = A + (size_t)N_NODES * 64;                    // 4 chunks, 12.8 MB

  float* z     = (float*)d_out;                 // N*64 fp32
  float* probs = z + (size_t)N_NODES * 64;      // E_Q*2 fp32

  int* gcur_d = gcur;
  int* gcur_s = gcur + NBUCK;

  const int gemmGrid = (N_NODES + 255) / 256;
  const int gathGrid = 4 * NBLK_N;

  // ---- POS relation ----
  hipMemsetAsync(gcur, 0, 2 * NBUCK * sizeof(int), stream);
  bin_edges<<<P1_BLOCKS, 256, 0, stream>>>(sp, dp, gcur_d, gcur_s, bin_d, bin_s);
  build_tables<<<2 * NBUCK, 256, 0, stream>>>(bin_d, gcur_d, bin_s, gcur_s,
                                              offs, degv, srclist, csrc);
  gemm_in_h<<<gemmGrid, 256, 0, stream>>>(x, W0p, csrc, A);
  gather_split<0><<<gathGrid, 256, 0, stream>>>(A, offs, degv, srclist, b0p, B,
                                                nullptr);
  gemm_mid_h<<<gemmGrid, 256, 0, stream>>>(B, W1p, csrc, A);
  gather_split<1><<<gathGrid, 256, 0, stream>>>(A, offs, degv, srclist, b1p,
                                                nullptr, z);

  // ---- NEG relation ---- (tables reused; pos consumers done)
  hipMemsetAsync(gcur, 0, 2 * NBUCK * sizeof(int), stream);
  bin_edges<<<P1_BLOCKS, 256, 0, stream>>>(sn, dn, gcur_d, gcur_s, bin_d, bin_s);
  build_tables<<<2 * NBUCK, 256, 0, stream>>>(bin_d, gcur_d, bin_s, gcur_s,
                                              offs, degv, srclist, csrc);
  gemm_in_h<<<gemmGrid, 256, 0, stream>>>(x, W0n, csrc, A);
  gather_split<0><<<gathGrid, 256, 0, stream>>>(A, offs, degv, srclist, b0n, B,
                                                nullptr);
  gemm_mid_h<<<gemmGrid, 256, 0, stream>>>(B, W1n, csrc, A);
  gather_split<2><<<gathGrid, 256, 0, stream>>>(A, offs, degv, srclist, b1n,
                                                nullptr, z);

  // ---- factorized classifier ----
  uv_kernel<<<(N_NODES * 64 + 255) / 256, 256, 0, stream>>>(z, Wc, uv);
  classify_kernel<<<(E_QQ + 255) / 256, 256, 0, stream>>>(uv, ei, bc, probs);
}